// Round 4
// baseline (164.899 us; speedup 1.0000x reference)
//
#include <hip/hip_runtime.h>

namespace {

constexpr int    TT    = 2048;
constexpr int    BB    = 128;
constexpr int    CHUNK = 8;                 // timesteps per shfl-scan chunk
constexpr int    TPB   = 512;               // threads per block (one timestep each)
constexpr int    BPB   = TT / TPB;          // 4 blocks per batch = chain depth
constexpr int    NBLK  = BB * BPB;          // 512 blocks = 2/CU * 256 CU (co-resident)
constexpr int    NCH   = TPB / CHUNK;       // 64 chunks per block
constexpr float  DT    = 0.02f;
constexpr size_t HALF  = (size_t)TT * BB * 16;

typedef float f32x4 __attribute__((ext_vector_type(4)));   // native vec for NT builtins

// C = A @ B, complex 4x4, row-major flat [16]
__device__ __forceinline__ void cmm(const float* __restrict__ ar, const float* __restrict__ ai,
                                    const float* __restrict__ br, const float* __restrict__ bi,
                                    float* __restrict__ cr, float* __restrict__ ci) {
#pragma unroll
    for (int i = 0; i < 4; ++i) {
#pragma unroll
        for (int j = 0; j < 4; ++j) {
            float sr = 0.f, si = 0.f;
#pragma unroll
            for (int k = 0; k < 4; ++k) {
                const float xr = ar[i * 4 + k], xi = ai[i * 4 + k];
                const float yr = br[k * 4 + j], yi = bi[k * 4 + j];
                sr = fmaf(xr, yr, sr);
                sr = fmaf(-xi, yi, sr);
                si = fmaf(xr, yi, si);
                si = fmaf(xi, yr, si);
            }
            cr[i * 4 + j] = sr;
            ci[i * 4 + j] = si;
        }
    }
}

// C += A @ B
__device__ __forceinline__ void cmm_acc(const float* __restrict__ ar, const float* __restrict__ ai,
                                        const float* __restrict__ br, const float* __restrict__ bi,
                                        float* __restrict__ cr, float* __restrict__ ci) {
#pragma unroll
    for (int i = 0; i < 4; ++i) {
#pragma unroll
        for (int j = 0; j < 4; ++j) {
            float sr = cr[i * 4 + j], si = ci[i * 4 + j];
#pragma unroll
            for (int k = 0; k < 4; ++k) {
                const float xr = ar[i * 4 + k], xi = ai[i * 4 + k];
                const float yr = br[k * 4 + j], yi = bi[k * 4 + j];
                sr = fmaf(xr, yr, sr);
                sr = fmaf(-xi, yi, sr);
                si = fmaf(xr, yi, si);
                si = fmaf(xi, yr, si);
            }
            cr[i * 4 + j] = sr;
            ci[i * 4 + j] = si;
        }
    }
}

// coherent-point load: relaxed agent-scope RMW (+0). Always executes at the
// device coherence point -> immune to stale clean copies in the local XCD L2,
// and emits NO buffer_inv / buffer_wbl2 cache-maintenance ops.
__device__ __forceinline__ unsigned int cp_load(unsigned int* p) {
    return __hip_atomic_fetch_add(p, 0u, __ATOMIC_RELAXED, __HIP_MEMORY_SCOPE_AGENT);
}

} // namespace

__global__ void k_init(unsigned int* flag) { flag[threadIdx.x] = 0u; }

// ---------------------------------------------------------------------------
// Single-pass chained scan. Block = 512 consecutive timesteps of one batch.
//   phase 1: A = -i*dt*H, expm (deg-4 PS), 8-lane Kogge-Stone chunk prefix.
//            L stays in f32 REGISTERS. Chunk totals -> LDS.
//   wave 0 : 6-round shfl scan over 64 chunk totals -> IP_c (stored to LDS).
//   chain  : block j spins on flag[bid-1] with relaxed fetch_add(0) (ONE
//            spinner per line, no inv storm), reads predecessor prefix P via
//            relaxed RMW loads, carr[c+1] = IP_c @ P, publishes payload
//            (relaxed stores) -> s_waitcnt vmcnt(0) -> relaxed flag store.
//            ZERO wbl2 / inv in the whole kernel.
//   phase 3: out[t][b] = L @ carr[chunk]. Nontemporal 64-B full-sector writes.
// Deadlock-free: VGPR<=128 + 16.5 KB LDS -> capacity 2 blocks/CU * 256 CU
// = 1024 >= grid 512; all blocks co-resident.
// ---------------------------------------------------------------------------
__global__ __launch_bounds__(TPB, 4) void k_main(
        const float* __restrict__ hr, const float* __restrict__ hi,
        const float* __restrict__ sr, const float* __restrict__ si,
        float* __restrict__ out, float* __restrict__ prefix,
        unsigned int* __restrict__ flag) {
    __shared__ float tot[32 * NCH];          // [e 0..31][c 0..63]  (later: IP)
    __shared__ float carr[32 * (NCH + 1)];   // [e][col]; col0 = P_prev, col c+1 = IP_c @ P

    const int tid    = threadIdx.x;
    const int bid    = blockIdx.x;
    const int blockT = bid & (BPB - 1);
    const int b      = bid >> 2;             // BPB == 4
    const int t      = blockT * TPB + tid;
    const int lane   = tid & 63;
    const int sub    = tid & (CHUNK - 1);
    const int c      = tid >> 3;             // chunk within block, 0..63

    // ---------------- phase 1: expm + chunk prefix (registers only) ----------
    float er[16], ei[16];
    {
        float a_r[16], a_i[16];
        const size_t gi = (size_t)b * TT + t;
        const f32x4* p4r = reinterpret_cast<const f32x4*>(hr) + gi * 4;
        const f32x4* p4i = reinterpret_cast<const f32x4*>(hi) + gi * 4;
#pragma unroll
        for (int v = 0; v < 4; ++v) {
            const f32x4 rr = __builtin_nontemporal_load(p4r + v);   // read-once stream
            const f32x4 im = __builtin_nontemporal_load(p4i + v);
#pragma unroll
            for (int e = 0; e < 4; ++e) {
                a_r[v * 4 + e] = DT * im[e];
                a_i[v * 4 + e] = -DT * rr[e];
            }
        }

        // E = (I + A) + A2 @ (I/2 + A/6 + A2/24)
        float a2r[16], a2i[16];
        cmm(a_r, a_i, a_r, a_i, a2r, a2i);
        float t6r[16], t6i[16];
#pragma unroll
        for (int e = 0; e < 16; ++e) {
            const float d = (e % 5 == 0) ? 1.0f : 0.0f;
            t6r[e] = fmaf(a_r[e], 1.f / 6.f, d * 0.5f);
            t6r[e] = fmaf(a2r[e], 1.f / 24.f, t6r[e]);
            t6i[e] = a_i[e] * (1.f / 6.f);
            t6i[e] = fmaf(a2i[e], 1.f / 24.f, t6i[e]);
            er[e]  = a_r[e] + d;
            ei[e]  = a_i[e];
        }
        cmm_acc(a2r, a2i, t6r, t6i, er, ei);
    }

    // 8-lane Kogge-Stone inclusive prefix (3 rounds)
#pragma unroll
    for (int d = 1; d < CHUNK; d <<= 1) {
        int src = lane - d;
        if (src < 0) src = 0;                // clamped junk, discarded by select
        float qr[16], qi[16];
#pragma unroll
        for (int e = 0; e < 16; ++e) {
            qr[e] = __shfl(er[e], src, 64);
            qi[e] = __shfl(ei[e], src, 64);
        }
        float nr[16], ni[16];
        cmm(er, ei, qr, qi, nr, ni);
        const bool pred = (sub >= d);
#pragma unroll
        for (int e = 0; e < 16; ++e) {
            er[e] = pred ? nr[e] : er[e];
            ei[e] = pred ? ni[e] : ei[e];
        }
    }

    // chunk totals -> LDS
    if (sub == CHUNK - 1) {
#pragma unroll
        for (int e = 0; e < 16; ++e) {
            tot[e * NCH + c]        = er[e];
            tot[(16 + e) * NCH + c] = ei[e];
        }
    }
    __syncthreads();

    // ---------------- wave 0: scan 64 chunk totals (shfl KS, 6 rounds) -------
    if (tid < 64) {
        float ipr[16], ipi[16];
#pragma unroll
        for (int e = 0; e < 16; ++e) {
            ipr[e] = tot[e * NCH + tid];
            ipi[e] = tot[(16 + e) * NCH + tid];
        }
#pragma unroll
        for (int d = 1; d < NCH; d <<= 1) {
            int src = tid - d;
            if (src < 0) src = 0;
            float qr[16], qi[16];
#pragma unroll
            for (int e = 0; e < 16; ++e) {
                qr[e] = __shfl(ipr[e], src, 64);
                qi[e] = __shfl(ipi[e], src, 64);
            }
            float nr[16], ni[16];
            cmm(ipr, ipi, qr, qi, nr, ni);
            const bool pred = (tid >= d);
#pragma unroll
            for (int e = 0; e < 16; ++e) {
                ipr[e] = pred ? nr[e] : ipr[e];
                ipi[e] = pred ? ni[e] : ipi[e];
            }
        }
        // store IP over tot (only wave 0 reads tot from here)
#pragma unroll
        for (int e = 0; e < 16; ++e) {
            tot[e * NCH + tid]        = ipr[e];
            tot[(16 + e) * NCH + tid] = ipi[e];
        }
    }

    // ---------------- chain: wait for predecessor's inclusive prefix ---------
    if (tid == 0 && blockT != 0) {
        while (cp_load(flag + (bid - 1)) == 0u) {
            __builtin_amdgcn_s_sleep(2);
        }
    }
    __syncthreads();   // orders spin before payload loads; IP now visible too

    if (tid < 32) {
        float pv;
        if (blockT == 0) {
            pv = (tid < 16) ? sr[b * 16 + tid] : si[b * 16 + (tid - 16)];
        } else {
            pv = __uint_as_float(cp_load(
                reinterpret_cast<unsigned int*>(prefix) + (size_t)(bid - 1) * 32 + tid));
        }
        carr[tid * (NCH + 1)] = pv;          // col 0 = P_prev (= carry of chunk 0)
    }
    __syncthreads();

    // ---------------- wave 0: carr[c+1] = IP_c @ P ; publish (fence-free) ----
    if (tid < 64) {
        float Ppr[16], Ppi[16];
#pragma unroll
        for (int e = 0; e < 16; ++e) {
            Ppr[e] = carr[e * (NCH + 1)];
            Ppi[e] = carr[(16 + e) * (NCH + 1)];
        }
        float cxr[16], cxi[16];
#pragma unroll
        for (int i = 0; i < 4; ++i) {
            float axr[4], axi[4];
#pragma unroll
            for (int k = 0; k < 4; ++k) {
                axr[k] = tot[(i * 4 + k) * NCH + tid];
                axi[k] = tot[(16 + i * 4 + k) * NCH + tid];
            }
#pragma unroll
            for (int j = 0; j < 4; ++j) {
                float s_r = 0.f, s_i = 0.f;
#pragma unroll
                for (int k = 0; k < 4; ++k) {
                    s_r = fmaf(axr[k], Ppr[k * 4 + j], s_r);
                    s_r = fmaf(-axi[k], Ppi[k * 4 + j], s_r);
                    s_i = fmaf(axr[k], Ppi[k * 4 + j], s_i);
                    s_i = fmaf(axi[k], Ppr[k * 4 + j], s_i);
                }
                cxr[i * 4 + j] = s_r;
                cxi[i * 4 + j] = s_i;
            }
        }
#pragma unroll
        for (int e = 0; e < 16; ++e) {
            carr[e * (NCH + 1) + tid + 1]        = cxr[e];
            carr[(16 + e) * (NCH + 1) + tid + 1] = cxi[e];
        }
        // publish block-inclusive prefix (carr col 64):
        //   relaxed payload stores -> wave-level vmcnt(0) (arrival at coherent
        //   point) -> relaxed flag store. No wbl2, no inv.
        if (blockT != BPB - 1) {
            if (tid < 32) {
                const float v = carr[tid * (NCH + 1) + NCH];  // lgkm-waited by compiler
                __hip_atomic_store(
                    reinterpret_cast<unsigned int*>(prefix) + (size_t)bid * 32 + tid,
                    __float_as_uint(v), __ATOMIC_RELAXED, __HIP_MEMORY_SCOPE_AGENT);
            }
            asm volatile("s_waitcnt vmcnt(0)" ::: "memory");
            if (tid == 0) {
                __hip_atomic_store(flag + bid, 1u, __ATOMIC_RELAXED,
                                   __HIP_MEMORY_SCOPE_AGENT);
            }
        }
    }
    __syncthreads();

    // ---------------- phase 3: out[t][b] = L @ carry(chunk) ------------------
    {
        float c_r[16], c_i[16];
#pragma unroll
        for (int e = 0; e < 16; ++e) {
            c_r[e] = carr[e * (NCH + 1) + c];        // broadcast per 8-lane group
            c_i[e] = carr[(16 + e) * (NCH + 1) + c];
        }
        float o_r[16], o_i[16];
        cmm(er, ei, c_r, c_i, o_r, o_i);

        // each half-matrix = one aligned 64-B sector per lane; write-once ->
        // nontemporal (keeps 67 MB of streaming stores out of the L2)
        const size_t oi = ((size_t)t * BB + b) * 16;
        f32x4* orp = reinterpret_cast<f32x4*>(out + oi);
        f32x4* oip = reinterpret_cast<f32x4*>(out + HALF + oi);
#pragma unroll
        for (int w = 0; w < 4; ++w) {
            f32x4 vr, vi;
#pragma unroll
            for (int e = 0; e < 4; ++e) {
                vr[e] = o_r[w * 4 + e];
                vi[e] = o_i[w * 4 + e];
            }
            __builtin_nontemporal_store(vr, orp + w);
            __builtin_nontemporal_store(vi, oip + w);
        }
    }
}

extern "C" void kernel_launch(void* const* d_in, const int* in_sizes, int n_in,
                              void* d_out, int out_size, void* d_ws, size_t ws_size,
                              hipStream_t stream) {
    const float* hr = (const float*)d_in[0];
    const float* hi = (const float*)d_in[1];
    const float* sr = (const float*)d_in[2];
    const float* si = (const float*)d_in[3];
    float* out    = (float*)d_out;
    float* prefix = (float*)d_ws;                                  // 512*32 floats = 64 KB
    unsigned int* flag = (unsigned int*)((float*)d_ws + (size_t)NBLK * 32);  // 512 uints

    k_init<<<1, NBLK, 0, stream>>>(flag);
    k_main<<<NBLK, TPB, 0, stream>>>(hr, hi, sr, si, out, prefix, flag);
}